// Round 8
// baseline (175.997 us; speedup 1.0000x reference)
//
#include <hip/hip_runtime.h>
#include <math.h>

// Burgers PINN: u = MLP(x,t) (2->10x7->1, tanh), outputs u, f, u_x, u_xx at 1M
// collocation points + plain forward at 3x16384 IC/boundary points.
// Forward-mode AD with 4 channels: (val, d/dx, d/dt, d2/dx2).
//
// R8: R5's intrinsic packed-fp32 bodies (best so far: 81.6 us) + merged
// single launch (R6) + amdgpu_waves_per_eu(2,2): 256-reg/wave budget and an
// explicit "2 waves/EU is all you get" — removes the allocator's incentive
// to squeeze arch VGPRs (stuck at 36-52 across R1-R7, forcing AGPR shuttle
// traffic worth ~2.4x instruction bloat).

#define NU_CONST 0.0031830988618379067f   // 0.01 / pi
#define TWO_OVER_LN2 2.8853900817779268f  // 2 / ln(2)

typedef float v2f __attribute__((ext_vector_type(2)));

__device__ __forceinline__ v2f splat2(float s) {
    v2f r; r.x = s; r.y = s; return r;
}
__device__ __forceinline__ v2f pk_fma(v2f a, v2f b, v2f c) {
    return __builtin_elementwise_fma(a, b, c);
}

__device__ __forceinline__ float fast_tanh(float x) {
    float e = __builtin_amdgcn_exp2f(x * TWO_OVER_LN2);
    float r = __builtin_amdgcn_rcpf(e + 1.0f);
    return fmaf(-2.0f, r, 1.0f);
}

// Packed tanh on a pair.
__device__ __forceinline__ v2f tanh2(v2f z2) {
    v2f a2 = z2 * splat2(TWO_OVER_LN2);
    v2f e2;
    e2.x = __builtin_amdgcn_exp2f(a2.x);
    e2.y = __builtin_amdgcn_exp2f(a2.y);
    v2f ep = e2 + splat2(1.0f);
    v2f r2;
    r2.x = __builtin_amdgcn_rcpf(ep.x);
    r2.y = __builtin_amdgcn_rcpf(ep.y);
    return pk_fma(splat2(-2.0f), r2, splat2(1.0f));
}

// One hidden 10->10 tanh layer, 4 AD channels, interleaved (max ILP),
// packed over output-neuron pairs. State arrays are scalar-indexed; the
// compiler folds splat2 broadcasts into VOP3P op_sel.
__device__ __forceinline__ void hidden10_ad(const float* __restrict__ W,
                                            const float* __restrict__ B,
                                            float h[10], float hx[10],
                                            float ht[10], float hxx[10]) {
    v2f Z[5], Zx[5], Zt[5], Zxx[5];
    {
        v2f hs   = splat2(h[0]);
        v2f hxs  = splat2(hx[0]);
        v2f hts  = splat2(ht[0]);
        v2f hxxs = splat2(hxx[0]);
#pragma unroll
        for (int jp = 0; jp < 5; ++jp) {
            v2f w2 = *(const v2f*)(W + 2 * jp);   // row 0, uniform -> s_load
            v2f b2 = *(const v2f*)(B + 2 * jp);
            Z[jp]   = pk_fma(hs, w2, b2);
            Zx[jp]  = hxs * w2;
            Zt[jp]  = hts * w2;
            Zxx[jp] = hxxs * w2;
        }
    }
#pragma unroll
    for (int i = 1; i < 10; ++i) {
        v2f hs   = splat2(h[i]);
        v2f hxs  = splat2(hx[i]);
        v2f hts  = splat2(ht[i]);
        v2f hxxs = splat2(hxx[i]);
#pragma unroll
        for (int jp = 0; jp < 5; ++jp) {
            v2f w2 = *(const v2f*)(W + i * 10 + 2 * jp);
            Z[jp]   = pk_fma(hs,   w2, Z[jp]);
            Zx[jp]  = pk_fma(hxs,  w2, Zx[jp]);
            Zt[jp]  = pk_fma(hts,  w2, Zt[jp]);
            Zxx[jp] = pk_fma(hxxs, w2, Zxx[jp]);
        }
    }
#pragma unroll
    for (int jp = 0; jp < 5; ++jp) {
        v2f v2v = tanh2(Z[jp]);
        v2f s2  = pk_fma(-v2v, v2v, splat2(1.0f));   // 1 - v^2
        v2f sx2 = s2 * Zx[jp];
        v2f m2v = splat2(-2.0f) * v2v;
        v2f htn2 = s2 * Zt[jp];
        // d2/dx2 tanh(z) = s*zxx + (-2v)*(sx*zx)
        v2f hxxn2 = pk_fma(s2, Zxx[jp], m2v * (sx2 * Zx[jp]));
        h[2*jp]   = v2v.x;   h[2*jp+1]   = v2v.y;
        hx[2*jp]  = sx2.x;   hx[2*jp+1]  = sx2.y;
        ht[2*jp]  = htn2.x;  ht[2*jp+1]  = htn2.y;
        hxx[2*jp] = hxxn2.x; hxx[2*jp+1] = hxxn2.y;
    }
}

// Values-only hidden layer (boundary/IC points), packed over j-pairs.
__device__ __forceinline__ void hidden10_fwd(const float* __restrict__ W,
                                             const float* __restrict__ B,
                                             float h[10]) {
    v2f Z[5];
    {
        v2f hs = splat2(h[0]);
#pragma unroll
        for (int jp = 0; jp < 5; ++jp) {
            v2f w2 = *(const v2f*)(W + 2 * jp);
            v2f b2 = *(const v2f*)(B + 2 * jp);
            Z[jp] = pk_fma(hs, w2, b2);
        }
    }
#pragma unroll
    for (int i = 1; i < 10; ++i) {
        v2f hs = splat2(h[i]);
#pragma unroll
        for (int jp = 0; jp < 5; ++jp) {
            v2f w2 = *(const v2f*)(W + i * 10 + 2 * jp);
            Z[jp] = pk_fma(hs, w2, Z[jp]);
        }
    }
#pragma unroll
    for (int jp = 0; jp < 5; ++jp) {
        v2f v2v = tanh2(Z[jp]);
        h[2*jp] = v2v.x;
        h[2*jp+1] = v2v.y;
    }
}

__global__ __launch_bounds__(256)
__attribute__((amdgpu_waves_per_eu(2, 2)))
void pinn_fused_kernel(
    const float* __restrict__ Xf,
    const float* __restrict__ X0, const float* __restrict__ XL,
    const float* __restrict__ XR,
    const float* __restrict__ W1, const float* __restrict__ b1,
    const float* __restrict__ W2, const float* __restrict__ b2,
    const float* __restrict__ W3, const float* __restrict__ b3,
    const float* __restrict__ W4, const float* __restrict__ b4,
    const float* __restrict__ W5, const float* __restrict__ b5,
    const float* __restrict__ W6, const float* __restrict__ b6,
    const float* __restrict__ W7, const float* __restrict__ b7,
    const float* __restrict__ W8, const float* __restrict__ b8,
    const float* __restrict__ W9, const float* __restrict__ b9,
    float* __restrict__ out_u, float* __restrict__ out_f,
    float* __restrict__ out_ux, float* __restrict__ out_uxx,
    float* __restrict__ O0, float* __restrict__ OL, float* __restrict__ OR_,
    int n_colloc_blocks, int NF, int N0) {
    if ((int)blockIdx.x < n_colloc_blocks) {
        // ---------------- collocation path: 4 AD channels ----------------
        int idx = blockIdx.x * blockDim.x + threadIdx.x;
        if (idx >= NF) return;
        float2 xt = ((const float2*)Xf)[idx];
        float x = xt.x;
        float t = xt.y;

        float h[10], hx[10], ht[10], hxx[10];
        // Layer 1: 2 -> 10, tanh. Seeds: dx=(1,0), dt=(0,1), dxx=0.
        {
            v2f xs = splat2(x);
            v2f ts = splat2(t);
#pragma unroll
            for (int jp = 0; jp < 5; ++jp) {
                v2f wx2 = *(const v2f*)(W1 + 2 * jp);        // W1 row 0
                v2f wt2 = *(const v2f*)(W1 + 10 + 2 * jp);   // W1 row 1
                v2f b2  = *(const v2f*)(b1 + 2 * jp);
                v2f z2  = pk_fma(xs, wx2, pk_fma(ts, wt2, b2));
                v2f v2v = tanh2(z2);
                v2f s2  = pk_fma(-v2v, v2v, splat2(1.0f));
                v2f sx2 = s2 * wx2;
                v2f m2v = splat2(-2.0f) * v2v;
                v2f st2 = s2 * wt2;
                v2f sxx2 = m2v * (sx2 * wx2);   // zxx = 0 at layer 1
                h[2*jp]   = v2v.x;  h[2*jp+1]   = v2v.y;
                hx[2*jp]  = sx2.x;  hx[2*jp+1]  = sx2.y;
                ht[2*jp]  = st2.x;  ht[2*jp+1]  = st2.y;
                hxx[2*jp] = sxx2.x; hxx[2*jp+1] = sxx2.y;
            }
        }

        hidden10_ad(W2, b2, h, hx, ht, hxx);
        hidden10_ad(W3, b3, h, hx, ht, hxx);
        hidden10_ad(W4, b4, h, hx, ht, hxx);
        hidden10_ad(W5, b5, h, hx, ht, hxx);
        hidden10_ad(W6, b6, h, hx, ht, hxx);
        hidden10_ad(W7, b7, h, hx, ht, hxx);
        hidden10_ad(W8, b8, h, hx, ht, hxx);

        // Layer 9: 10 -> 1, linear.
        float u = b9[0], ux = 0.f, ut = 0.f, uxx = 0.f;
#pragma unroll
        for (int i = 0; i < 10; ++i) {
            float w = W9[i];
            u   = fmaf(h[i],   w, u);
            ux  = fmaf(hx[i],  w, ux);
            ut  = fmaf(ht[i],  w, ut);
            uxx = fmaf(hxx[i], w, uxx);
        }

        out_u[idx]   = u;
        out_ux[idx]  = ux;
        out_uxx[idx] = uxx;
        out_f[idx]   = fmaf(u, ux, ut) - NU_CONST * uxx;  // u_t + u*u_x - nu*u_xx
    } else {
        // ---------------- forward-only path: IC + boundaries ----------------
        int idx = (blockIdx.x - n_colloc_blocks) * blockDim.x + threadIdx.x;
        if (idx >= 3 * N0) return;
        const float* X;
        float* O;
        int k;
        if (idx < N0)            { X = X0; O = O0;  k = idx; }
        else if (idx < 2 * N0)   { X = XL; O = OL;  k = idx - N0; }
        else                     { X = XR; O = OR_; k = idx - 2 * N0; }

        float2 xt = ((const float2*)X)[k];
        float x = xt.x;
        float t = xt.y;

        float h[10];
#pragma unroll
        for (int j = 0; j < 10; ++j) {
            float z = fmaf(x, W1[j], fmaf(t, W1[10 + j], b1[j]));
            h[j] = fast_tanh(z);
        }
        hidden10_fwd(W2, b2, h);
        hidden10_fwd(W3, b3, h);
        hidden10_fwd(W4, b4, h);
        hidden10_fwd(W5, b5, h);
        hidden10_fwd(W6, b6, h);
        hidden10_fwd(W7, b7, h);
        hidden10_fwd(W8, b8, h);

        float u = b9[0];
#pragma unroll
        for (int i = 0; i < 10; ++i) u = fmaf(h[i], W9[i], u);
        O[k] = u;
    }
}

extern "C" void kernel_launch(void* const* d_in, const int* in_sizes, int n_in,
                              void* d_out, int out_size, void* d_ws, size_t ws_size,
                              hipStream_t stream) {
    const float* Xf = (const float*)d_in[0];
    const float* X0 = (const float*)d_in[1];
    const float* XL = (const float*)d_in[2];
    const float* XR = (const float*)d_in[3];
    const float* W[9];
    const float* B[9];
    for (int i = 0; i < 9; ++i) {
        W[i] = (const float*)d_in[4 + 2 * i];
        B[i] = (const float*)d_in[5 + 2 * i];
    }
    int NF = in_sizes[0] / 2;
    int N0 = in_sizes[1] / 2;
    int NB = in_sizes[2] / 2;

    float* out = (float*)d_out;
    float* out_u   = out;                         // u_pred_f      [NF]
    float* out_0   = out + NF;                    // u_pred_0      [N0]
    float* out_bl  = out + NF + N0;               // u_pred_b_left [NB]
    float* out_br  = out + NF + N0 + NB;          // u_pred_b_right[NB]
    float* out_f   = out + NF + N0 + 2 * NB;      // f             [NF]
    float* out_ux  = out_f + NF;                  // u_x           [NF]
    float* out_uxx = out_ux + NF;                 // u_xx          [NF]

    int n_colloc_blocks = (NF + 255) / 256;
    int n_fwd_blocks    = (3 * N0 + 255) / 256;
    dim3 blk(256);
    dim3 grd(n_colloc_blocks + n_fwd_blocks);
    pinn_fused_kernel<<<grd, blk, 0, stream>>>(
        Xf, X0, XL, XR,
        W[0], B[0], W[1], B[1], W[2], B[2], W[3], B[3], W[4], B[4],
        W[5], B[5], W[6], B[6], W[7], B[7], W[8], B[8],
        out_u, out_f, out_ux, out_uxx,
        out_0, out_bl, out_br,
        n_colloc_blocks, NF, N0);
}

// Round 9
// 170.874 us; speedup vs baseline: 1.0300x; 1.0300x over previous
//
#include <hip/hip_runtime.h>
#include <math.h>

// Burgers PINN: u = MLP(x,t) (2->10x7->1, tanh), outputs u, f, u_x, u_xx at 1M
// collocation points + plain forward at 3x16384 IC/boundary points.
// Forward-mode AD with 4 channels: (val, d/dx, d/dt, d2/dx2).
//
// R9: R5's packed-fp32 body (measured-best instruction stream: ~9500
// busy-cyc/wave, ~96% issue-efficient under the pk=4cyc model) + merged
// launch + amdgpu_waves_per_eu(4,6). min=4 keeps the allocator honest
// (grant cap 128 >> the ~52 this body needs -> no squeeze), max=6 raises
// the residency ceiling that R5's (3,4) capped at 3 waves/SIMD.
// Goal: VALUBusy 79% -> ~90% on the SAME instruction stream.

#define NU_CONST 0.0031830988618379067f   // 0.01 / pi
#define TWO_OVER_LN2 2.8853900817779268f  // 2 / ln(2)

typedef float v2f __attribute__((ext_vector_type(2)));

__device__ __forceinline__ v2f splat2(float s) {
    v2f r; r.x = s; r.y = s; return r;
}
__device__ __forceinline__ v2f pk_fma(v2f a, v2f b, v2f c) {
    return __builtin_elementwise_fma(a, b, c);
}

__device__ __forceinline__ float fast_tanh(float x) {
    float e = __builtin_amdgcn_exp2f(x * TWO_OVER_LN2);
    float r = __builtin_amdgcn_rcpf(e + 1.0f);
    return fmaf(-2.0f, r, 1.0f);
}

// Packed tanh on a pair.
__device__ __forceinline__ v2f tanh2(v2f z2) {
    v2f a2 = z2 * splat2(TWO_OVER_LN2);
    v2f e2;
    e2.x = __builtin_amdgcn_exp2f(a2.x);
    e2.y = __builtin_amdgcn_exp2f(a2.y);
    v2f ep = e2 + splat2(1.0f);
    v2f r2;
    r2.x = __builtin_amdgcn_rcpf(ep.x);
    r2.y = __builtin_amdgcn_rcpf(ep.y);
    return pk_fma(splat2(-2.0f), r2, splat2(1.0f));
}

// One hidden 10->10 tanh layer, 4 AD channels, interleaved (max ILP),
// packed over output-neuron pairs.
__device__ __forceinline__ void hidden10_ad(const float* __restrict__ W,
                                            const float* __restrict__ B,
                                            float h[10], float hx[10],
                                            float ht[10], float hxx[10]) {
    v2f Z[5], Zx[5], Zt[5], Zxx[5];
    {
        v2f hs   = splat2(h[0]);
        v2f hxs  = splat2(hx[0]);
        v2f hts  = splat2(ht[0]);
        v2f hxxs = splat2(hxx[0]);
#pragma unroll
        for (int jp = 0; jp < 5; ++jp) {
            v2f w2 = *(const v2f*)(W + 2 * jp);   // row 0, uniform -> s_load
            v2f b2 = *(const v2f*)(B + 2 * jp);
            Z[jp]   = pk_fma(hs, w2, b2);
            Zx[jp]  = hxs * w2;
            Zt[jp]  = hts * w2;
            Zxx[jp] = hxxs * w2;
        }
    }
#pragma unroll
    for (int i = 1; i < 10; ++i) {
        v2f hs   = splat2(h[i]);
        v2f hxs  = splat2(hx[i]);
        v2f hts  = splat2(ht[i]);
        v2f hxxs = splat2(hxx[i]);
#pragma unroll
        for (int jp = 0; jp < 5; ++jp) {
            v2f w2 = *(const v2f*)(W + i * 10 + 2 * jp);
            Z[jp]   = pk_fma(hs,   w2, Z[jp]);
            Zx[jp]  = pk_fma(hxs,  w2, Zx[jp]);
            Zt[jp]  = pk_fma(hts,  w2, Zt[jp]);
            Zxx[jp] = pk_fma(hxxs, w2, Zxx[jp]);
        }
    }
#pragma unroll
    for (int jp = 0; jp < 5; ++jp) {
        v2f v2v = tanh2(Z[jp]);
        v2f s2  = pk_fma(-v2v, v2v, splat2(1.0f));   // 1 - v^2
        v2f sx2 = s2 * Zx[jp];
        v2f m2v = splat2(-2.0f) * v2v;
        v2f htn2 = s2 * Zt[jp];
        // d2/dx2 tanh(z) = s*zxx + (-2v)*(sx*zx)
        v2f hxxn2 = pk_fma(s2, Zxx[jp], m2v * (sx2 * Zx[jp]));
        h[2*jp]   = v2v.x;   h[2*jp+1]   = v2v.y;
        hx[2*jp]  = sx2.x;   hx[2*jp+1]  = sx2.y;
        ht[2*jp]  = htn2.x;  ht[2*jp+1]  = htn2.y;
        hxx[2*jp] = hxxn2.x; hxx[2*jp+1] = hxxn2.y;
    }
}

// Values-only hidden layer (boundary/IC points), packed over j-pairs.
__device__ __forceinline__ void hidden10_fwd(const float* __restrict__ W,
                                             const float* __restrict__ B,
                                             float h[10]) {
    v2f Z[5];
    {
        v2f hs = splat2(h[0]);
#pragma unroll
        for (int jp = 0; jp < 5; ++jp) {
            v2f w2 = *(const v2f*)(W + 2 * jp);
            v2f b2 = *(const v2f*)(B + 2 * jp);
            Z[jp] = pk_fma(hs, w2, b2);
        }
    }
#pragma unroll
    for (int i = 1; i < 10; ++i) {
        v2f hs = splat2(h[i]);
#pragma unroll
        for (int jp = 0; jp < 5; ++jp) {
            v2f w2 = *(const v2f*)(W + i * 10 + 2 * jp);
            Z[jp] = pk_fma(hs, w2, Z[jp]);
        }
    }
#pragma unroll
    for (int jp = 0; jp < 5; ++jp) {
        v2f v2v = tanh2(Z[jp]);
        h[2*jp] = v2v.x;
        h[2*jp+1] = v2v.y;
    }
}

__global__ __launch_bounds__(256)
__attribute__((amdgpu_waves_per_eu(4, 6)))
void pinn_fused_kernel(
    const float* __restrict__ Xf,
    const float* __restrict__ X0, const float* __restrict__ XL,
    const float* __restrict__ XR,
    const float* __restrict__ W1, const float* __restrict__ b1,
    const float* __restrict__ W2, const float* __restrict__ b2,
    const float* __restrict__ W3, const float* __restrict__ b3,
    const float* __restrict__ W4, const float* __restrict__ b4,
    const float* __restrict__ W5, const float* __restrict__ b5,
    const float* __restrict__ W6, const float* __restrict__ b6,
    const float* __restrict__ W7, const float* __restrict__ b7,
    const float* __restrict__ W8, const float* __restrict__ b8,
    const float* __restrict__ W9, const float* __restrict__ b9,
    float* __restrict__ out_u, float* __restrict__ out_f,
    float* __restrict__ out_ux, float* __restrict__ out_uxx,
    float* __restrict__ O0, float* __restrict__ OL, float* __restrict__ OR_,
    int n_colloc_blocks, int NF, int N0) {
    if ((int)blockIdx.x < n_colloc_blocks) {
        // ---------------- collocation path: 4 AD channels ----------------
        int idx = blockIdx.x * blockDim.x + threadIdx.x;
        if (idx >= NF) return;
        float2 xt = ((const float2*)Xf)[idx];
        float x = xt.x;
        float t = xt.y;

        float h[10], hx[10], ht[10], hxx[10];
        // Layer 1: 2 -> 10, tanh. Seeds: dx=(1,0), dt=(0,1), dxx=0.
        {
            v2f xs = splat2(x);
            v2f ts = splat2(t);
#pragma unroll
            for (int jp = 0; jp < 5; ++jp) {
                v2f wx2 = *(const v2f*)(W1 + 2 * jp);        // W1 row 0
                v2f wt2 = *(const v2f*)(W1 + 10 + 2 * jp);   // W1 row 1
                v2f b2  = *(const v2f*)(b1 + 2 * jp);
                v2f z2  = pk_fma(xs, wx2, pk_fma(ts, wt2, b2));
                v2f v2v = tanh2(z2);
                v2f s2  = pk_fma(-v2v, v2v, splat2(1.0f));
                v2f sx2 = s2 * wx2;
                v2f m2v = splat2(-2.0f) * v2v;
                v2f st2 = s2 * wt2;
                v2f sxx2 = m2v * (sx2 * wx2);   // zxx = 0 at layer 1
                h[2*jp]   = v2v.x;  h[2*jp+1]   = v2v.y;
                hx[2*jp]  = sx2.x;  hx[2*jp+1]  = sx2.y;
                ht[2*jp]  = st2.x;  ht[2*jp+1]  = st2.y;
                hxx[2*jp] = sxx2.x; hxx[2*jp+1] = sxx2.y;
            }
        }

        hidden10_ad(W2, b2, h, hx, ht, hxx);
        hidden10_ad(W3, b3, h, hx, ht, hxx);
        hidden10_ad(W4, b4, h, hx, ht, hxx);
        hidden10_ad(W5, b5, h, hx, ht, hxx);
        hidden10_ad(W6, b6, h, hx, ht, hxx);
        hidden10_ad(W7, b7, h, hx, ht, hxx);
        hidden10_ad(W8, b8, h, hx, ht, hxx);

        // Layer 9: 10 -> 1, linear.
        float u = b9[0], ux = 0.f, ut = 0.f, uxx = 0.f;
#pragma unroll
        for (int i = 0; i < 10; ++i) {
            float w = W9[i];
            u   = fmaf(h[i],   w, u);
            ux  = fmaf(hx[i],  w, ux);
            ut  = fmaf(ht[i],  w, ut);
            uxx = fmaf(hxx[i], w, uxx);
        }

        out_u[idx]   = u;
        out_ux[idx]  = ux;
        out_uxx[idx] = uxx;
        out_f[idx]   = fmaf(u, ux, ut) - NU_CONST * uxx;  // u_t + u*u_x - nu*u_xx
    } else {
        // ---------------- forward-only path: IC + boundaries ----------------
        int idx = (blockIdx.x - n_colloc_blocks) * blockDim.x + threadIdx.x;
        if (idx >= 3 * N0) return;
        const float* X;
        float* O;
        int k;
        if (idx < N0)            { X = X0; O = O0;  k = idx; }
        else if (idx < 2 * N0)   { X = XL; O = OL;  k = idx - N0; }
        else                     { X = XR; O = OR_; k = idx - 2 * N0; }

        float2 xt = ((const float2*)X)[k];
        float x = xt.x;
        float t = xt.y;

        float h[10];
#pragma unroll
        for (int j = 0; j < 10; ++j) {
            float z = fmaf(x, W1[j], fmaf(t, W1[10 + j], b1[j]));
            h[j] = fast_tanh(z);
        }
        hidden10_fwd(W2, b2, h);
        hidden10_fwd(W3, b3, h);
        hidden10_fwd(W4, b4, h);
        hidden10_fwd(W5, b5, h);
        hidden10_fwd(W6, b6, h);
        hidden10_fwd(W7, b7, h);
        hidden10_fwd(W8, b8, h);

        float u = b9[0];
#pragma unroll
        for (int i = 0; i < 10; ++i) u = fmaf(h[i], W9[i], u);
        O[k] = u;
    }
}

extern "C" void kernel_launch(void* const* d_in, const int* in_sizes, int n_in,
                              void* d_out, int out_size, void* d_ws, size_t ws_size,
                              hipStream_t stream) {
    const float* Xf = (const float*)d_in[0];
    const float* X0 = (const float*)d_in[1];
    const float* XL = (const float*)d_in[2];
    const float* XR = (const float*)d_in[3];
    const float* W[9];
    const float* B[9];
    for (int i = 0; i < 9; ++i) {
        W[i] = (const float*)d_in[4 + 2 * i];
        B[i] = (const float*)d_in[5 + 2 * i];
    }
    int NF = in_sizes[0] / 2;
    int N0 = in_sizes[1] / 2;
    int NB = in_sizes[2] / 2;

    float* out = (float*)d_out;
    float* out_u   = out;                         // u_pred_f      [NF]
    float* out_0   = out + NF;                    // u_pred_0      [N0]
    float* out_bl  = out + NF + N0;               // u_pred_b_left [NB]
    float* out_br  = out + NF + N0 + NB;          // u_pred_b_right[NB]
    float* out_f   = out + NF + N0 + 2 * NB;      // f             [NF]
    float* out_ux  = out_f + NF;                  // u_x           [NF]
    float* out_uxx = out_ux + NF;                 // u_xx          [NF]

    int n_colloc_blocks = (NF + 255) / 256;
    int n_fwd_blocks    = (3 * N0 + 255) / 256;
    dim3 blk(256);
    dim3 grd(n_colloc_blocks + n_fwd_blocks);
    pinn_fused_kernel<<<grd, blk, 0, stream>>>(
        Xf, X0, XL, XR,
        W[0], B[0], W[1], B[1], W[2], B[2], W[3], B[3], W[4], B[4],
        W[5], B[5], W[6], B[6], W[7], B[7], W[8], B[8],
        out_u, out_f, out_ux, out_uxx,
        out_0, out_bl, out_br,
        n_colloc_blocks, NF, N0);
}

// Round 10
// 168.205 us; speedup vs baseline: 1.0463x; 1.0159x over previous
//
#include <hip/hip_runtime.h>
#include <math.h>

// Burgers PINN: u = MLP(x,t) (2->10x7->1, tanh), outputs u, f, u_x, u_xx at 1M
// collocation points + plain forward at 3x16384 IC/boundary points.
// Forward-mode AD with 4 channels: (val, d/dx, d/dt, d2/dx2).
//
// R10: TWO points per thread. Measured invariants (R5-R9): stream fixed at
// ~9200 busy-cyc/wave, VALUBusy capped ~78% at any occupancy 1.7-4.4 w/SIMD
// -> idle is phase-correlated (per-layer weight s_load lgkm waits: 100
// SGPRs/layer vs 112 budget, + tanh dep-chains). Batching 2 pts/thread:
// each weight s_load feeds 8 pk_fmas (was 4), 2 independent dep-graphs
// double intra-wave ILP. waves_per_eu(2,2) = honest 256-reg grant (R8).

#define NU_CONST 0.0031830988618379067f   // 0.01 / pi
#define TWO_OVER_LN2 2.8853900817779268f  // 2 / ln(2)

typedef float v2f __attribute__((ext_vector_type(2)));

__device__ __forceinline__ v2f splat2(float s) {
    v2f r; r.x = s; r.y = s; return r;
}
__device__ __forceinline__ v2f pk_fma(v2f a, v2f b, v2f c) {
    return __builtin_elementwise_fma(a, b, c);
}

__device__ __forceinline__ float fast_tanh(float x) {
    float e = __builtin_amdgcn_exp2f(x * TWO_OVER_LN2);
    float r = __builtin_amdgcn_rcpf(e + 1.0f);
    return fmaf(-2.0f, r, 1.0f);
}

// Packed tanh on a pair.
__device__ __forceinline__ v2f tanh2(v2f z2) {
    v2f a2 = z2 * splat2(TWO_OVER_LN2);
    v2f e2;
    e2.x = __builtin_amdgcn_exp2f(a2.x);
    e2.y = __builtin_amdgcn_exp2f(a2.y);
    v2f ep = e2 + splat2(1.0f);
    v2f r2;
    r2.x = __builtin_amdgcn_rcpf(ep.x);
    r2.y = __builtin_amdgcn_rcpf(ep.y);
    return pk_fma(splat2(-2.0f), r2, splat2(1.0f));
}

// One hidden 10->10 tanh layer, 4 AD channels, TWO points per thread.
// Each weight pair w2 is loaded once and feeds 8 pk_fmas.
__device__ __forceinline__ void hidden10_ad_x2(const float* __restrict__ W,
                                               const float* __restrict__ B,
                                               float h[2][10], float hx[2][10],
                                               float ht[2][10], float hxx[2][10]) {
    v2f Z[2][5], Zx[2][5], Zt[2][5], Zxx[2][5];
#pragma unroll
    for (int jp = 0; jp < 5; ++jp) {
        v2f w2 = *(const v2f*)(W + 2 * jp);   // row 0, uniform -> s_load
        v2f b2 = *(const v2f*)(B + 2 * jp);
#pragma unroll
        for (int p = 0; p < 2; ++p) {
            Z[p][jp]   = pk_fma(splat2(h[p][0]), w2, b2);
            Zx[p][jp]  = splat2(hx[p][0]) * w2;
            Zt[p][jp]  = splat2(ht[p][0]) * w2;
            Zxx[p][jp] = splat2(hxx[p][0]) * w2;
        }
    }
#pragma unroll
    for (int i = 1; i < 10; ++i) {
#pragma unroll
        for (int jp = 0; jp < 5; ++jp) {
            v2f w2 = *(const v2f*)(W + i * 10 + 2 * jp);
#pragma unroll
            for (int p = 0; p < 2; ++p) {
                Z[p][jp]   = pk_fma(splat2(h[p][i]),   w2, Z[p][jp]);
                Zx[p][jp]  = pk_fma(splat2(hx[p][i]),  w2, Zx[p][jp]);
                Zt[p][jp]  = pk_fma(splat2(ht[p][i]),  w2, Zt[p][jp]);
                Zxx[p][jp] = pk_fma(splat2(hxx[p][i]), w2, Zxx[p][jp]);
            }
        }
    }
#pragma unroll
    for (int p = 0; p < 2; ++p) {
#pragma unroll
        for (int jp = 0; jp < 5; ++jp) {
            v2f v2v = tanh2(Z[p][jp]);
            v2f s2  = pk_fma(-v2v, v2v, splat2(1.0f));   // 1 - v^2
            v2f sx2 = s2 * Zx[p][jp];
            v2f m2v = splat2(-2.0f) * v2v;
            v2f htn2 = s2 * Zt[p][jp];
            // d2/dx2 tanh(z) = s*zxx + (-2v)*(sx*zx)
            v2f hxxn2 = pk_fma(s2, Zxx[p][jp], m2v * (sx2 * Zx[p][jp]));
            h[p][2*jp]   = v2v.x;   h[p][2*jp+1]   = v2v.y;
            hx[p][2*jp]  = sx2.x;   hx[p][2*jp+1]  = sx2.y;
            ht[p][2*jp]  = htn2.x;  ht[p][2*jp+1]  = htn2.y;
            hxx[p][2*jp] = hxxn2.x; hxx[p][2*jp+1] = hxxn2.y;
        }
    }
}

// Values-only hidden layer (boundary/IC points), packed over j-pairs.
__device__ __forceinline__ void hidden10_fwd(const float* __restrict__ W,
                                             const float* __restrict__ B,
                                             float h[10]) {
    v2f Z[5];
    {
        v2f hs = splat2(h[0]);
#pragma unroll
        for (int jp = 0; jp < 5; ++jp) {
            v2f w2 = *(const v2f*)(W + 2 * jp);
            v2f b2 = *(const v2f*)(B + 2 * jp);
            Z[jp] = pk_fma(hs, w2, b2);
        }
    }
#pragma unroll
    for (int i = 1; i < 10; ++i) {
        v2f hs = splat2(h[i]);
#pragma unroll
        for (int jp = 0; jp < 5; ++jp) {
            v2f w2 = *(const v2f*)(W + i * 10 + 2 * jp);
            Z[jp] = pk_fma(hs, w2, Z[jp]);
        }
    }
#pragma unroll
    for (int jp = 0; jp < 5; ++jp) {
        v2f v2v = tanh2(Z[jp]);
        h[2*jp] = v2v.x;
        h[2*jp+1] = v2v.y;
    }
}

__global__ __launch_bounds__(256)
__attribute__((amdgpu_waves_per_eu(2, 2)))
void pinn_fused_kernel(
    const float* __restrict__ Xf,
    const float* __restrict__ X0, const float* __restrict__ XL,
    const float* __restrict__ XR,
    const float* __restrict__ W1, const float* __restrict__ b1,
    const float* __restrict__ W2, const float* __restrict__ b2,
    const float* __restrict__ W3, const float* __restrict__ b3,
    const float* __restrict__ W4, const float* __restrict__ b4,
    const float* __restrict__ W5, const float* __restrict__ b5,
    const float* __restrict__ W6, const float* __restrict__ b6,
    const float* __restrict__ W7, const float* __restrict__ b7,
    const float* __restrict__ W8, const float* __restrict__ b8,
    const float* __restrict__ W9, const float* __restrict__ b9,
    float* __restrict__ out_u, float* __restrict__ out_f,
    float* __restrict__ out_ux, float* __restrict__ out_uxx,
    float* __restrict__ O0, float* __restrict__ OL, float* __restrict__ OR_,
    int n_colloc_blocks, int NF2, int N0) {
    if ((int)blockIdx.x < n_colloc_blocks) {
        // ------------- collocation path: 2 points, 4 AD channels -------------
        int gid = blockIdx.x * blockDim.x + threadIdx.x;   // pair index
        if (gid >= NF2) return;
        // Points 2*gid and 2*gid+1: one float4 = (x0,t0,x1,t1).
        float4 xt2 = ((const float4*)Xf)[gid];
        float xin[2], tin[2];
        xin[0] = xt2.x; tin[0] = xt2.y;
        xin[1] = xt2.z; tin[1] = xt2.w;

        float h[2][10], hx[2][10], ht[2][10], hxx[2][10];
        // Layer 1: 2 -> 10, tanh. Seeds: dx=(1,0), dt=(0,1), dxx=0.
#pragma unroll
        for (int jp = 0; jp < 5; ++jp) {
            v2f wx2 = *(const v2f*)(W1 + 2 * jp);        // W1 row 0
            v2f wt2 = *(const v2f*)(W1 + 10 + 2 * jp);   // W1 row 1
            v2f b2  = *(const v2f*)(b1 + 2 * jp);
#pragma unroll
            for (int p = 0; p < 2; ++p) {
                v2f z2  = pk_fma(splat2(xin[p]), wx2,
                                 pk_fma(splat2(tin[p]), wt2, b2));
                v2f v2v = tanh2(z2);
                v2f s2  = pk_fma(-v2v, v2v, splat2(1.0f));
                v2f sx2 = s2 * wx2;
                v2f m2v = splat2(-2.0f) * v2v;
                v2f st2 = s2 * wt2;
                v2f sxx2 = m2v * (sx2 * wx2);   // zxx = 0 at layer 1
                h[p][2*jp]   = v2v.x;  h[p][2*jp+1]   = v2v.y;
                hx[p][2*jp]  = sx2.x;  hx[p][2*jp+1]  = sx2.y;
                ht[p][2*jp]  = st2.x;  ht[p][2*jp+1]  = st2.y;
                hxx[p][2*jp] = sxx2.x; hxx[p][2*jp+1] = sxx2.y;
            }
        }

        hidden10_ad_x2(W2, b2, h, hx, ht, hxx);
        hidden10_ad_x2(W3, b3, h, hx, ht, hxx);
        hidden10_ad_x2(W4, b4, h, hx, ht, hxx);
        hidden10_ad_x2(W5, b5, h, hx, ht, hxx);
        hidden10_ad_x2(W6, b6, h, hx, ht, hxx);
        hidden10_ad_x2(W7, b7, h, hx, ht, hxx);
        hidden10_ad_x2(W8, b8, h, hx, ht, hxx);

        // Layer 9: 10 -> 1, linear. Packed pairwise dot + horizontal add.
        float u[2], ux[2], ut[2], uxx[2];
#pragma unroll
        for (int p = 0; p < 2; ++p) {
            v2f w0 = *(const v2f*)(W9);
            v2f u2   = splat2(h[p][0]);     // placeholder init below
            // init with jp=0 products
            u2       = *(v2f*)&w0, u2 = w0; // (avoided; do it directly)
            v2f hu, hxu, htu, hxxu;
            hu.x   = h[p][0];   hu.y   = h[p][1];
            hxu.x  = hx[p][0];  hxu.y  = hx[p][1];
            htu.x  = ht[p][0];  htu.y  = ht[p][1];
            hxxu.x = hxx[p][0]; hxxu.y = hxx[p][1];
            v2f su   = hu   * w0;
            v2f sux  = hxu  * w0;
            v2f sut  = htu  * w0;
            v2f suxx = hxxu * w0;
#pragma unroll
            for (int jp = 1; jp < 5; ++jp) {
                v2f w2 = *(const v2f*)(W9 + 2 * jp);
                v2f a, b, c, d;
                a.x = h[p][2*jp];   a.y = h[p][2*jp+1];
                b.x = hx[p][2*jp];  b.y = hx[p][2*jp+1];
                c.x = ht[p][2*jp];  c.y = ht[p][2*jp+1];
                d.x = hxx[p][2*jp]; d.y = hxx[p][2*jp+1];
                su   = pk_fma(a, w2, su);
                sux  = pk_fma(b, w2, sux);
                sut  = pk_fma(c, w2, sut);
                suxx = pk_fma(d, w2, suxx);
            }
            u[p]   = b9[0] + (su.x + su.y);
            ux[p]  = sux.x + sux.y;
            ut[p]  = sut.x + sut.y;
            uxx[p] = suxx.x + suxx.y;
        }

        float2 st;
        st.x = u[0]; st.y = u[1];
        ((float2*)out_u)[gid] = st;
        st.x = ux[0]; st.y = ux[1];
        ((float2*)out_ux)[gid] = st;
        st.x = uxx[0]; st.y = uxx[1];
        ((float2*)out_uxx)[gid] = st;
        st.x = fmaf(u[0], ux[0], ut[0]) - NU_CONST * uxx[0];
        st.y = fmaf(u[1], ux[1], ut[1]) - NU_CONST * uxx[1];
        ((float2*)out_f)[gid] = st;   // u_t + u*u_x - nu*u_xx
    } else {
        // ---------------- forward-only path: IC + boundaries ----------------
        int idx = (blockIdx.x - n_colloc_blocks) * blockDim.x + threadIdx.x;
        if (idx >= 3 * N0) return;
        const float* X;
        float* O;
        int k;
        if (idx < N0)            { X = X0; O = O0;  k = idx; }
        else if (idx < 2 * N0)   { X = XL; O = OL;  k = idx - N0; }
        else                     { X = XR; O = OR_; k = idx - 2 * N0; }

        float2 xt = ((const float2*)X)[k];
        float x = xt.x;
        float t = xt.y;

        float h[10];
#pragma unroll
        for (int j = 0; j < 10; ++j) {
            float z = fmaf(x, W1[j], fmaf(t, W1[10 + j], b1[j]));
            h[j] = fast_tanh(z);
        }
        hidden10_fwd(W2, b2, h);
        hidden10_fwd(W3, b3, h);
        hidden10_fwd(W4, b4, h);
        hidden10_fwd(W5, b5, h);
        hidden10_fwd(W6, b6, h);
        hidden10_fwd(W7, b7, h);
        hidden10_fwd(W8, b8, h);

        float u = b9[0];
#pragma unroll
        for (int i = 0; i < 10; ++i) u = fmaf(h[i], W9[i], u);
        O[k] = u;
    }
}

extern "C" void kernel_launch(void* const* d_in, const int* in_sizes, int n_in,
                              void* d_out, int out_size, void* d_ws, size_t ws_size,
                              hipStream_t stream) {
    const float* Xf = (const float*)d_in[0];
    const float* X0 = (const float*)d_in[1];
    const float* XL = (const float*)d_in[2];
    const float* XR = (const float*)d_in[3];
    const float* W[9];
    const float* B[9];
    for (int i = 0; i < 9; ++i) {
        W[i] = (const float*)d_in[4 + 2 * i];
        B[i] = (const float*)d_in[5 + 2 * i];
    }
    int NF = in_sizes[0] / 2;
    int N0 = in_sizes[1] / 2;
    int NB = in_sizes[2] / 2;
    int NF2 = NF / 2;   // pairs of points (NF = 1048576, even)

    float* out = (float*)d_out;
    float* out_u   = out;                         // u_pred_f      [NF]
    float* out_0   = out + NF;                    // u_pred_0      [N0]
    float* out_bl  = out + NF + N0;               // u_pred_b_left [NB]
    float* out_br  = out + NF + N0 + NB;          // u_pred_b_right[NB]
    float* out_f   = out + NF + N0 + 2 * NB;      // f             [NF]
    float* out_ux  = out_f + NF;                  // u_x           [NF]
    float* out_uxx = out_ux + NF;                 // u_xx          [NF]

    int n_colloc_blocks = (NF2 + 255) / 256;
    int n_fwd_blocks    = (3 * N0 + 255) / 256;
    dim3 blk(256);
    dim3 grd(n_colloc_blocks + n_fwd_blocks);
    pinn_fused_kernel<<<grd, blk, 0, stream>>>(
        Xf, X0, XL, XR,
        W[0], B[0], W[1], B[1], W[2], B[2], W[3], B[3], W[4], B[4],
        W[5], B[5], W[6], B[6], W[7], B[7], W[8], B[8],
        out_u, out_f, out_ux, out_uxx,
        out_0, out_bl, out_br,
        n_colloc_blocks, NF2, N0);
}